// Round 8
// baseline (227.227 us; speedup 1.0000x reference)
//
#include <hip/hip_runtime.h>
#include <hip/hip_bf16.h>
#include <cstdint>

// ---------------------------------------------------------------------------
// MLPDecoder: logit[e] = relu([zu, zv, |zu-zv|] @ W1 + b1) @ W2 + b2
//   z: [100000,128] f32, edge_index: [2,E] int, W1: [384,128], b1:[128],
//   W2: [128,1], b2:[1].  Output: [E] f32.
//
// R8: N-split W1 across blocks -> 48KB LDS -> 3 blocks/CU = 6 waves/SIMD.
//   R7 evidence: spill fixed (WRITE 1.95MB, VGPR 88) but MfmaUtil 18% /
//   VALUBusy 29% at 1 block/CU (96KB LDS, 2 waves/SIMD): pipes serialized,
//   not overlapped. Per-CU pipe loads (MFMA 3.7k, LDS 4.6k, VALU 5k cyc/tile)
//   vs 17k measured => TLP-starved. Fix: each block holds ONE n-half of W1
//   (384 x 64 cols = 48KB); 768 blocks (384/half) -> 3 blocks/CU.
//   Per-wave K-loop identical to R7 (proven VGPR=88, no spill). Wave covers
//   its block's whole n-half -> NO cross-wave reduce, NO per-tile barrier.
//   out pre-filled with b2 (init kernel); halves atomicAdd their partial.
// ---------------------------------------------------------------------------

typedef __bf16 bf16_t;
typedef __bf16 bf16x8 __attribute__((ext_vector_type(8)));
typedef float  floatx4 __attribute__((ext_vector_type(4)));

#define DIM 128
#define E_TILE 256          // edges per block-tile (8 waves x 32 edges)
#define N_KSTEP 12          // 384 / 32
#define N_NTILE 8           // 128 / 16
#define GRID_PER_HALF 384   // 768 blocks total -> 3 blocks/CU

// --- init out with b2 -------------------------------------------------------
__global__ void init_out_kernel(float* __restrict__ out, const float* __restrict__ b2, int E) {
    int i = blockIdx.x * 256 + threadIdx.x;
    if (i < E) out[i] = b2[0];
}

// --- cast z fp32 -> bf16 ----------------------------------------------------
__global__ void cast_z_kernel(const float* __restrict__ z, bf16_t* __restrict__ zb, int n) {
    int idx = (blockIdx.x * 256 + threadIdx.x) * 8;
    if (idx + 8 > n) return;
    const float4* src = reinterpret_cast<const float4*>(z + idx);
    float4 a = src[0], b = src[1];
    bf16x8 o;
    o[0] = (bf16_t)a.x; o[1] = (bf16_t)a.y; o[2] = (bf16_t)a.z; o[3] = (bf16_t)a.w;
    o[4] = (bf16_t)b.x; o[5] = (bf16_t)b.y; o[6] = (bf16_t)b.z; o[7] = (bf16_t)b.w;
    *reinterpret_cast<bf16x8*>(zb + idx) = o;
}

// --- pack W1 [384,128] f32 row-major -> MFMA B-fragment order bf16 ----------
// frag index f = (kstep*8 + ntile); element j of lane l:
//   B[k = kstep*32 + (l>>4)*8 + j][n = ntile*16 + (l&15)]
__global__ void pack_w1_kernel(const float* __restrict__ W1, bf16_t* __restrict__ Wp) {
    int f = blockIdx.x * 256 + threadIdx.x;     // 0 .. 12*8*64-1
    if (f >= N_KSTEP * N_NTILE * 64) return;
    int lane = f & 63;
    int nt   = (f >> 6) & 7;
    int ks   = f >> 9;
    int n  = nt * 16 + (lane & 15);
    int k0 = ks * 32 + (lane >> 4) * 8;
    bf16x8 o;
#pragma unroll
    for (int j = 0; j < 8; ++j) o[j] = (bf16_t)W1[(k0 + j) * DIM + n];
    reinterpret_cast<bf16x8*>(Wp)[f] = o;
}

// --- main fused kernel ------------------------------------------------------
// grid (GRID_PER_HALF, 2): blockIdx.y = n-half h. Block: 512 thr = 8 waves,
// each wave 32 edges x the block's 64 n-cols.
template <bool PRECAST>
__global__ __launch_bounds__(512, 2)
void decode_kernel(const void* __restrict__ zsrc,
                   const int* __restrict__ ei,       // [2*E]
                   const bf16_t* __restrict__ Wp,    // packed W1 (96KB)
                   const float* __restrict__ b1,
                   const float* __restrict__ W2,
                   float* __restrict__ out, int E) {
    __shared__ __align__(16) bf16_t Bsm[N_KSTEP * 4 * 64 * 8];   // 48 KiB

    const int tid = threadIdx.x;
    const int h   = blockIdx.y;      // n-half

    // ---- stage this half of packed W1 into LDS (48KB = 3072 uint4) ----
    {
        const uint4* src = reinterpret_cast<const uint4*>(Wp);
        uint4* dst = reinterpret_cast<uint4*>(Bsm);
#pragma unroll
        for (int i = 0; i < 6; ++i) {
            int linear = i * 512 + tid;               // (ks*4+ntl)*64+lane
            int ks  = linear >> 8;
            int rem = linear & 255;                   // ntl*64+lane
            dst[linear] = src[ks * 512 + h * 256 + rem];
        }
    }
    __syncthreads();    // the only barrier in the kernel

    const int wave = tid >> 6, lane = tid & 63;      // wave = wm (0..7)
    const int l15 = lane & 15, quad = lane >> 4;

    // ---- epilogue params (this block's n-half) ----
    float b1v[4], w2v[4];
#pragma unroll
    for (int nt = 0; nt < 4; ++nt) {
        int n = (h * 4 + nt) * 16 + l15;
        b1v[nt] = b1[n];
        w2v[nt] = W2[n];
    }

    const int ntiles = (E + E_TILE - 1) / E_TILE;

    // gather one 16B chunk of zu/zv for (mt, c): cols [c*32+quad*8, +8)
    auto gatherChunk = [&](bf16x8& du, bf16x8& dv, int nu, int nv, int c) {
        if (PRECAST) {
            const bf16_t* zb = (const bf16_t*)zsrc;
            du = *reinterpret_cast<const bf16x8*>(zb + (size_t)nu * DIM + c * 32 + quad * 8);
            dv = *reinterpret_cast<const bf16x8*>(zb + (size_t)nv * DIM + c * 32 + quad * 8);
        } else {
            const float* zf = (const float*)zsrc;
            const float4* pu = reinterpret_cast<const float4*>(zf + (size_t)nu * DIM + c * 32 + quad * 8);
            const float4* pv = reinterpret_cast<const float4*>(zf + (size_t)nv * DIM + c * 32 + quad * 8);
            float4 a = pu[0], b = pu[1];
            bf16x8 o;
            o[0] = (bf16_t)a.x; o[1] = (bf16_t)a.y; o[2] = (bf16_t)a.z; o[3] = (bf16_t)a.w;
            o[4] = (bf16_t)b.x; o[5] = (bf16_t)b.y; o[6] = (bf16_t)b.z; o[7] = (bf16_t)b.w;
            du = o;
            a = pv[0]; b = pv[1];
            o[0] = (bf16_t)a.x; o[1] = (bf16_t)a.y; o[2] = (bf16_t)a.z; o[3] = (bf16_t)a.w;
            o[4] = (bf16_t)b.x; o[5] = (bf16_t)b.y; o[6] = (bf16_t)b.z; o[7] = (bf16_t)b.w;
            dv = o;
        }
    };

    // load the 4 B-frags of this half for kstep ks
    auto loadB4 = [&](bf16x8* dst, int ks) {
#pragma unroll
        for (int nt = 0; nt < 4; ++nt)
            dst[nt] = *reinterpret_cast<const bf16x8*>(
                &Bsm[(size_t)((ks * 4 + nt) * 64 + lane) * 8]);
    };

    auto loadIdx = [&](int t, int mt, int& nu, int& nv) {
        int e = t * E_TILE + wave * 32 + mt * 16 + l15;
        if (e >= E) e = E - 1;                   // clamp: compute-only, store guarded
        nu = ei[e];
        nv = ei[E + e];
    };

    // ---- A-chunk ping-pong (2 chunks live at a time, 32 arch regs) ----
    struct AChunk { bf16x8 u[2], v[2]; };
    AChunk A0, A1;
    int cnu[2], cnv[2], nnu[2], nnv[2];

    // prologue: indices + chunk 0 of the first tile
#pragma unroll
    for (int mt = 0; mt < 2; ++mt) loadIdx(blockIdx.x, mt, cnu[mt], cnv[mt]);
#pragma unroll
    for (int mt = 0; mt < 2; ++mt)
        gatherChunk(A0.u[mt], A0.v[mt], cnu[mt], cnv[mt], 0);

    // ---- persistent grid-stride loop ----
    for (int t = blockIdx.x; t < ntiles; t += GRID_PER_HALF) {
        // next tile's node indices (needed by the g=3 prefetch)
#pragma unroll
        for (int mt = 0; mt < 2; ++mt) loadIdx(t + GRID_PER_HALF, mt, nnu[mt], nnv[mt]);

        floatx4 acc[2][4];
#pragma unroll
        for (int mt = 0; mt < 2; ++mt)
#pragma unroll
            for (int nt = 0; nt < 4; ++nt) acc[mt][nt] = (floatx4)0.0f;

        // 4 c-groups; group g computes ks {g, 4+g, 8+g} from CUR while
        // prefetching chunk g+1 (or next tile's chunk 0) into NXT.
#pragma unroll
        for (int g = 0; g < 4; ++g) {
            AChunk& cur = (g & 1) ? A1 : A0;
            AChunk& nxt = (g & 1) ? A0 : A1;

            // issue prefetch first; result not needed until group g+1
            if (g < 3) {
#pragma unroll
                for (int mt = 0; mt < 2; ++mt)
                    gatherChunk(nxt.u[mt], nxt.v[mt], cnu[mt], cnv[mt], g + 1);
            } else {
#pragma unroll
                for (int mt = 0; mt < 2; ++mt)
                    gatherChunk(nxt.u[mt], nxt.v[mt], nnu[mt], nnv[mt], 0);
            }

            {   // ks = g : A = zu chunk g
                bf16x8 bc[4];
                loadB4(bc, g);
#pragma unroll
                for (int mt = 0; mt < 2; ++mt)
#pragma unroll
                    for (int nt = 0; nt < 4; ++nt)
                        acc[mt][nt] = __builtin_amdgcn_mfma_f32_16x16x32_bf16(
                            cur.u[mt], bc[nt], acc[mt][nt], 0, 0, 0);
            }
            {   // ks = 4+g : A = zv chunk g
                bf16x8 bc[4];
                loadB4(bc, 4 + g);
#pragma unroll
                for (int mt = 0; mt < 2; ++mt)
#pragma unroll
                    for (int nt = 0; nt < 4; ++nt)
                        acc[mt][nt] = __builtin_amdgcn_mfma_f32_16x16x32_bf16(
                            cur.v[mt], bc[nt], acc[mt][nt], 0, 0, 0);
            }
            {   // ks = 8+g : A = |zu - zv| chunk g
                bf16x8 bc[4];
                loadB4(bc, 8 + g);
#pragma unroll
                for (int mt = 0; mt < 2; ++mt) {
                    bf16x8 u = cur.u[mt], v = cur.v[mt];
                    bf16x8 d;
#pragma unroll
                    for (int j = 0; j < 8; ++j)
                        d[j] = (bf16_t)fabsf((float)u[j] - (float)v[j]);
#pragma unroll
                    for (int nt = 0; nt < 4; ++nt)
                        acc[mt][nt] = __builtin_amdgcn_mfma_f32_16x16x32_bf16(
                            d, bc[nt], acc[mt][nt], 0, 0, 0);
                }
            }
        }
        // after g=3: A0 holds chunk 0 of tile t+GRID_PER_HALF
#pragma unroll
        for (int mt = 0; mt < 2; ++mt) { cnu[mt] = nnu[mt]; cnv[mt] = nnv[mt]; }

        // ---- epilogue: bias + relu + dot(W2-half), butterfly, atomicAdd ----
        // C/D layout: n = (h*4+nt)*16 + l15, m = quad*4 + r
#pragma unroll
        for (int mt = 0; mt < 2; ++mt)
#pragma unroll
            for (int r = 0; r < 4; ++r) {
                float s = 0.f;
#pragma unroll
                for (int nt = 0; nt < 4; ++nt) {
                    float hh = acc[mt][nt][r] + b1v[nt];
                    hh = fmaxf(hh, 0.f);
                    s += hh * w2v[nt];
                }
                s += __shfl_xor(s, 1);
                s += __shfl_xor(s, 2);
                s += __shfl_xor(s, 4);
                s += __shfl_xor(s, 8);
                if (l15 == 0) {
                    int e = t * E_TILE + wave * 32 + mt * 16 + quad * 4 + r;
                    if (e < E) atomicAdd(&out[e], s);
                }
            }
    }
}

// ---------------------------------------------------------------------------
extern "C" void kernel_launch(void* const* d_in, const int* in_sizes, int n_in,
                              void* d_out, int out_size, void* d_ws, size_t ws_size,
                              hipStream_t stream) {
    const float* z  = (const float*)d_in[0];
    const int*   ei = (const int*)d_in[1];
    const float* W1 = (const float*)d_in[2];
    const float* b1 = (const float*)d_in[3];
    const float* W2 = (const float*)d_in[4];
    const float* b2 = (const float*)d_in[5];
    float* out = (float*)d_out;

    const int E  = in_sizes[1] / 2;
    const int zn = in_sizes[0];

    const size_t zb_bytes = (size_t)zn * sizeof(bf16_t);
    const size_t wp_bytes = (size_t)N_KSTEP * N_NTILE * 64 * 16;  // 98304
    const bool precast = ws_size >= zb_bytes + wp_bytes;

    bf16_t* zb = (bf16_t*)d_ws;
    bf16_t* wp = precast ? (bf16_t*)((char*)d_ws + zb_bytes) : (bf16_t*)d_ws;

    hipLaunchKernelGGL(init_out_kernel, dim3((E + 255) / 256), dim3(256),
                       0, stream, out, b2, E);
    hipLaunchKernelGGL(pack_w1_kernel, dim3((N_KSTEP * N_NTILE * 64 + 255) / 256),
                       dim3(256), 0, stream, W1, wp);

    if (precast) {
        hipLaunchKernelGGL(cast_z_kernel, dim3((zn / 8 + 255) / 256), dim3(256),
                           0, stream, z, zb, zn);
        hipLaunchKernelGGL((decode_kernel<true>), dim3(GRID_PER_HALF, 2), dim3(512), 0,
                           stream, (const void*)zb, ei, wp, b1, W2, out, E);
    } else {
        hipLaunchKernelGGL((decode_kernel<false>), dim3(GRID_PER_HALF, 2), dim3(512), 0,
                           stream, (const void*)z, ei, wp, b1, W2, out, E);
    }
}